// Round 11
// baseline (560.112 us; speedup 1.0000x reference)
//
#include <hip/hip_runtime.h>

#define N_NODES 50000
#define N_EDGES 800000

#define SCAN_CHUNK 256
#define SCAN_BLOCKS ((N_NODES + SCAN_CHUNK - 1) / SCAN_CHUNK) // 196

static inline size_t alignUp(size_t x, size_t a) { return (x + a - 1) & ~(a - 1); }

// ---------------- CSR build ----------------

__global__ void k_zero_i32(int* __restrict__ p, int n) {
    int i = blockIdx.x * 256 + threadIdx.x;
    if (i < n) p[i] = 0;
}

// count degrees; first 128 threads also zero the csr_col over-read pad,
// first 8 zero the per-panel work queue (consumed later by k_aggx)
__global__ void k_count(const int* __restrict__ row, int* __restrict__ count,
                        int* __restrict__ pad, int* __restrict__ queue) {
    int e = blockIdx.x * 256 + threadIdx.x;
    if (e < 128) pad[e] = 0;
    if (e < 8) queue[e] = 0;
    if (e < N_EDGES) atomicAdd(&count[row[e]], 1);
}

__global__ void k_blocksum(const int* __restrict__ count, int* __restrict__ bsum) {
    __shared__ int s[256];
    int t = threadIdx.x;
    int i = blockIdx.x * 256 + t;
    int v = (i < N_NODES) ? count[i] : 0;
    s[t] = v;
    __syncthreads();
    for (int off = 128; off > 0; off >>= 1) {
        if (t < off) s[t] += s[t + off];
        __syncthreads();
    }
    if (t == 0) bsum[blockIdx.x] = s[0];
}

__global__ void k_scan_bsum(int* __restrict__ bsum) {
    __shared__ int s[256];
    int t = threadIdx.x;
    int v = (t < SCAN_BLOCKS) ? bsum[t] : 0;
    s[t] = v;
    __syncthreads();
    for (int off = 1; off < 256; off <<= 1) {
        int add = (t >= off) ? s[t - off] : 0;
        __syncthreads();
        s[t] += add;
        __syncthreads();
    }
    if (t < SCAN_BLOCKS) bsum[t] = s[t] - v; // exclusive
}

__global__ void k_scan_final(const int* __restrict__ count, const int* __restrict__ bsum,
                             int* __restrict__ offsets, int* __restrict__ cursor,
                             float* __restrict__ dinv) {
    __shared__ int s[256];
    int t = threadIdx.x;
    int i = blockIdx.x * 256 + t;
    int v = (i < N_NODES) ? count[i] : 0;
    s[t] = v;
    __syncthreads();
    for (int off = 1; off < 256; off <<= 1) {
        int add = (t >= off) ? s[t - off] : 0;
        __syncthreads();
        s[t] += add;
        __syncthreads();
    }
    if (i < N_NODES) {
        int excl = s[t] - v + bsum[blockIdx.x];
        offsets[i] = excl;
        cursor[i]  = excl;
        dinv[i]    = rsqrtf((float)(v + 1)); // +1 self-loop; always > 0
    }
}

__global__ void k_scatter(const int* __restrict__ row, const int* __restrict__ col,
                          int* __restrict__ cursor, int* __restrict__ csr_col) {
    int e = blockIdx.x * 256 + threadIdx.x;
    if (e < N_EDGES) {
        int r = row[e];
        int pos = atomicAdd(&cursor[r], 1);
        csr_col[pos] = col[e];
    }
}

// ---------------- prescale: o[i,:] = dinv[i] * f[i,:]  (F=64, float4 grain) ----

__global__ void k_prescale64(const float* __restrict__ f, const float* __restrict__ dinv,
                             float* __restrict__ o) {
    int i = blockIdx.x * 256 + threadIdx.x; // float4 index
    if (i < N_NODES * 16) {
        int node = i >> 4;
        float d = dinv[node];
        float4 v = reinterpret_cast<const float4*>(f)[i];
        reinterpret_cast<float4*>(o)[i] = make_float4(v.x * d, v.y * d, v.z * d, v.w * d);
    }
}

// ---------------- R4-proven F=64 aggregation (wave per node, float2 lanes) ----
// out[i] = dinv_i * ( h'[i] + sum_c h'[c] ) (+bias), h' = dinv .* h

template <bool BIAS>
__global__ __launch_bounds__(256) void k_agg64(const float* __restrict__ hs, float* __restrict__ out,
        const int* __restrict__ csr_col, const int* __restrict__ offsets,
        const int* __restrict__ count, const float* __restrict__ dinv,
        const float* __restrict__ bias) {
    int lane = threadIdx.x & 63;
    int node = blockIdx.x * 4 + (threadIdx.x >> 6);
    int half = lane >> 5;
    int f2 = lane & 31;
    const float2* h2 = reinterpret_cast<const float2*>(hs);

    float ax[8], ay[8];
#pragma unroll
    for (int u = 0; u < 8; u++) { ax[u] = 0.f; ay[u] = 0.f; }

    int n = count[node];
    const int* cp = csr_col + offsets[node];

    int e = 0;
    for (; e + 16 <= n; e += 16) {
        int c[8];
#pragma unroll
        for (int u = 0; u < 8; u++) c[u] = cp[e + 2 * u + half];
#pragma unroll
        for (int u = 0; u < 8; u++) {
            float2 v = h2[(size_t)c[u] * 32 + f2];
            ax[u] += v.x; ay[u] += v.y;
        }
    }
    if (e < n) { // one predicated batch covers rem 1..15
#pragma unroll
        for (int u = 0; u < 8; u++) {
            int eid = e + 2 * u + half;
            int c = cp[eid]; // padded, safe
            float2 v = h2[(size_t)c * 32 + f2];
            if (eid < n) { ax[u] += v.x; ay[u] += v.y; }
        }
    }

    float sx = 0.f, sy = 0.f;
#pragma unroll
    for (int u = 0; u < 8; u++) { sx += ax[u]; sy += ay[u]; }
    sx += __shfl_xor(sx, 32);
    sy += __shfl_xor(sy, 32);
    if (half == 0) {
        float2 self = h2[(size_t)node * 32 + f2];
        float d = dinv[node];
        float ox = (sx + self.x) * d, oy = (sy + self.y) * d;
        if (BIAS) { ox += bias[2 * f2]; oy += bias[2 * f2 + 1]; }
        reinterpret_cast<float2*>(out)[(size_t)node * 32 + f2] = make_float2(ox, oy);
    }
}

// ---------------- Layer-2 (F=128) PHYSICAL-XCD-pinned panel aggregation ----
// R8 (blockIdx%8) and R10 (blockIdx/chunk) both failed to localize panels.
// This version reads the PHYSICAL XCD id via s_getreg(HW_REG_XCC_ID)
// [measured: learn_hip m09] and claims chunks of its own XCD's panel from a
// per-panel atomic queue; overflow blocks steal from other panels.
// Deadlock-free: a failed probe on panel q (t >= CPP) implies q fully
// claimed; failing all 8 implies all work done. Writes are disjoint per
// (node, panel) and every chunk is claimed exactly once -> output is
// deterministic and mapping-independent (locality is perf-only).

__global__ __launch_bounds__(256) void k_aggx(const float* __restrict__ hs,
        float* __restrict__ out, const int* __restrict__ csr_col,
        const int* __restrict__ offsets, const int* __restrict__ count,
        const float* __restrict__ dinv, int* __restrict__ queue) {
    constexpr int CPP = 3125; // chunks per panel: 3125 * 16 nodes = 50000

    __shared__ int s_panel, s_chunk;
    if (threadIdx.x == 0) {
        unsigned xcc = 0;
        asm volatile("s_getreg_b32 %0, hwreg(HW_REG_XCC_ID)" : "=s"(xcc));
        int p = (int)(xcc & 7);
        int c = atomicAdd(&queue[p], 1);
        if (c >= CPP) { // own panel done: steal
            for (int i = 1; i <= 8; i++) {
                int q = (p + i) & 7;
                c = atomicAdd(&queue[q], 1);
                if (c < CPP) { p = q; break; }
            }
        }
        s_panel = p;
        s_chunk = c;
    }
    __syncthreads();
    int panel = s_panel;
    int chunk = s_chunk;
    if (chunk >= CPP) return; // all work claimed elsewhere

    int lane = threadIdx.x & 63;
    int node0 = chunk * 16 + (threadIdx.x >> 6) * 4; // this wave's 4 nodes
    int cc = lane & 3;
    int es = lane >> 2; // edge slot 0..15
    uint32_t fo = (uint32_t)(panel * 64 + cc * 16);  // byte offset within 512B row
    const char* base = (const char*)hs;

    int myn = node0 + (lane >> 4); // node this lane reports for (k = lane>>4)
    bool vn = myn < N_NODES;
    int n_l = vn ? count[myn] : 0;
    int off_l = vn ? offsets[myn] : 0;
    const int* cp_l = csr_col + off_l;

    int n0 = __shfl(n_l, 0), n1 = __shfl(n_l, 16);
    int n2 = __shfl(n_l, 32), n3 = __shfl(n_l, 48);
    int maxn = max(max(n0, n1), max(n2, n3));

    float4 a0 = make_float4(0.f, 0.f, 0.f, 0.f);
    float4 a1 = a0, a2 = a0, a3 = a0;

    for (int e = 0; e < maxn; e += 16) {
        // one instruction: 4 nodes x 16 csr entries (pad(128) covers tail)
        int c_all = cp_l[e + (lane & 15)];
        int c0 = __shfl(c_all, es);
        int c1 = __shfl(c_all, 16 + es);
        int c2 = __shfl(c_all, 32 + es);
        int c3 = __shfl(c_all, 48 + es);
        // one gather instruction per node: 16 edges x 4 chunks = 64 lanes
        float4 v0 = *reinterpret_cast<const float4*>(base + (((uint32_t)c0 << 9) + fo));
        float4 v1 = *reinterpret_cast<const float4*>(base + (((uint32_t)c1 << 9) + fo));
        float4 v2 = *reinterpret_cast<const float4*>(base + (((uint32_t)c2 << 9) + fo));
        float4 v3 = *reinterpret_cast<const float4*>(base + (((uint32_t)c3 << 9) + fo));
        int ei = e + es;
        if (ei < n0) { a0.x += v0.x; a0.y += v0.y; a0.z += v0.z; a0.w += v0.w; }
        if (ei < n1) { a1.x += v1.x; a1.y += v1.y; a1.z += v1.z; a1.w += v1.w; }
        if (ei < n2) { a2.x += v2.x; a2.y += v2.y; a2.z += v2.z; a2.w += v2.w; }
        if (ei < n3) { a3.x += v3.x; a3.y += v3.y; a3.z += v3.z; a3.w += v3.w; }
    }

    // reduce over the 16 edge slots (lane bits 2..5), keep cc distinct
#pragma unroll
    for (int s = 4; s < 64; s <<= 1) {
        a0.x += __shfl_xor(a0.x, s); a0.y += __shfl_xor(a0.y, s);
        a0.z += __shfl_xor(a0.z, s); a0.w += __shfl_xor(a0.w, s);
        a1.x += __shfl_xor(a1.x, s); a1.y += __shfl_xor(a1.y, s);
        a1.z += __shfl_xor(a1.z, s); a1.w += __shfl_xor(a1.w, s);
        a2.x += __shfl_xor(a2.x, s); a2.y += __shfl_xor(a2.y, s);
        a2.z += __shfl_xor(a2.z, s); a2.w += __shfl_xor(a2.w, s);
        a3.x += __shfl_xor(a3.x, s); a3.y += __shfl_xor(a3.y, s);
        a3.z += __shfl_xor(a3.z, s); a3.w += __shfl_xor(a3.w, s);
    }

    // lanes l = k*16 + cc (i.e. (l>>2)&3 == 0) write node k's chunk cc
    if (((lane >> 2) & 3) == 0 && vn) {
        int k = lane >> 4;
        float4 tot = (k == 0) ? a0 : ((k == 1) ? a1 : ((k == 2) ? a2 : a3));
        float4 self = *reinterpret_cast<const float4*>(base + (((uint32_t)myn << 9) + fo));
        float d = dinv[myn];
        *reinterpret_cast<float4*>((char*)out + (((uint32_t)myn << 9) + fo)) =
            make_float4((tot.x + self.x) * d, (tot.y + self.y) * d,
                        (tot.z + self.z) * d, (tot.w + self.w) * d);
    }
}

// ---------------- fp32 GEMM (R4 known-good: BK=32, BN=64) ----------------
// out[r,c] = post( x[r,:] @ W[:,c] ), post = (+bias) -> relu -> (*dinv[r])
// __launch_bounds__(256,4) caps VGPR at 128 (R3 spilled at 256 VGPR);
// '#pragma unroll 1' on the K-tile loop prevents whole-kernel flattening.
// RPT-dependent branches are `if constexpr` (R6 compile failure).

template <int K, int NOUT, int BM, bool RELU, bool BIAS, bool SCALE>
__global__ __launch_bounds__(256, 4) void k_gemm(const float* __restrict__ x,
        const float* __restrict__ W, const float* __restrict__ bias,
        const float* __restrict__ dinv, float* __restrict__ out, int nrows) {
    constexpr int BK = 32, BN = 64;
    constexpr int NCB = NOUT / BN;  // column blocks per row
    constexpr int RPT = BM / 16;    // rows per thread (8 or 4)
    __shared__ float xt[BK * BM];
    __shared__ float wt[BK * BN];

    int tid = threadIdx.x;
    int rg = tid & 15;  // row group
    int cg = tid >> 4;  // col group: cols cg*4..+3 of the 64-col strip
    int row0 = (blockIdx.x / NCB) * BM;
    int col0 = (blockIdx.x % NCB) * BN;

    float acc[RPT][4] = {};

#pragma unroll 1
    for (int kk = 0; kk < K; kk += BK) {
        __syncthreads();
        // ---- x tile: BM rows x 32 k, coalesced float4, swizzled transpose store
#pragma unroll
        for (int t = 0; t < BM / 32; ++t) {
            int idx = tid + t * 256;
            int r = idx >> 3;
            int kc = (idx & 7) * 4;
            float4 v = make_float4(0.f, 0.f, 0.f, 0.f);
            int gr = row0 + r;
            if (gr < nrows) v = *reinterpret_cast<const float4*>(&x[(size_t)gr * K + kk + kc]);
            int rc = r ^ kc; // kc in {0..28}: swizzle within 32-row stripe
            xt[(kc + 0) * BM + rc] = v.x;
            xt[(kc + 1) * BM + rc] = v.y;
            xt[(kc + 2) * BM + rc] = v.z;
            xt[(kc + 3) * BM + rc] = v.w;
        }
        // ---- W tile: 32 k x 64 n
#pragma unroll
        for (int t = 0; t < 2; ++t) {
            int idx = tid + t * 256;
            int k = idx >> 4;
            int c = (idx & 15) * 4;
            *reinterpret_cast<float4*>(&wt[k * BN + c]) =
                *reinterpret_cast<const float4*>(&W[(size_t)(kk + k) * NOUT + col0 + c]);
        }
        __syncthreads();

#pragma unroll
        for (int k = 0; k < BK; ++k) {
            int s = k & 28;
            float4 wv = *reinterpret_cast<const float4*>(&wt[k * BN + cg * 4]);
            float wr[4] = {wv.x, wv.y, wv.z, wv.w};
            float xr[RPT];
            float4 x0 = *reinterpret_cast<const float4*>(&xt[k * BM + ((rg * 4) ^ s)]);
            xr[0] = x0.x; xr[1] = x0.y; xr[2] = x0.z; xr[3] = x0.w;
            if constexpr (RPT == 8) {
                float4 x1 = *reinterpret_cast<const float4*>(&xt[k * BM + (((rg * 4) ^ s) + 64)]);
                xr[4] = x1.x; xr[5] = x1.y; xr[6] = x1.z; xr[7] = x1.w;
            }
#pragma unroll
            for (int a = 0; a < RPT; a++)
#pragma unroll
                for (int b = 0; b < 4; b++) acc[a][b] += xr[a] * wr[b];
        }
    }

    float bv[4];
    if (BIAS) {
#pragma unroll
        for (int b = 0; b < 4; b++) bv[b] = bias[col0 + cg * 4 + b];
    }
#pragma unroll
    for (int a = 0; a < RPT; a++) {
        int r = rg * 4 + (a & 3) + ((a >= 4) ? 64 : 0);
        int gr = row0 + r;
        if (gr >= nrows) continue;
        float d = SCALE ? dinv[gr] : 1.f;
        float o[4];
#pragma unroll
        for (int b = 0; b < 4; b++) {
            float v = acc[a][b];
            if (BIAS) v += bv[b];
            if (RELU) v = fmaxf(v, 0.f);
            o[b] = v * d;
        }
        *reinterpret_cast<float4*>(&out[(size_t)gr * NOUT + col0 + cg * 4]) =
            make_float4(o[0], o[1], o[2], o[3]);
    }
}

// ---------------- launch ----------------

extern "C" void kernel_launch(void* const* d_in, const int* in_sizes, int n_in,
                              void* d_out, int out_size, void* d_ws, size_t ws_size,
                              hipStream_t stream) {
    const float* feat = (const float*)d_in[0]; // [N, 64]
    const float* W1 = (const float*)d_in[1];   // [64, 128]
    const float* b1 = (const float*)d_in[2];
    const float* W2 = (const float*)d_in[3];   // [128, 128]
    const float* b2 = (const float*)d_in[4];
    const float* W3 = (const float*)d_in[5];   // [128, 64]
    const float* b3 = (const float*)d_in[6];
    const int* ei = (const int*)d_in[7];       // [2, E]
    const int* row = ei;
    const int* col = ei + N_EDGES;
    float* out = (float*)d_out;

    // workspace bump allocator (256B aligned)
    char* ws = (char*)d_ws;
    size_t off = 0;
    auto alloc = [&](size_t bytes) {
        void* p = ws + off;
        off = alignUp(off + bytes, 256);
        return p;
    };
    float* B0      = (float*)alloc((size_t)N_NODES * 128 * 4);
    float* B1      = (float*)alloc((size_t)N_NODES * 128 * 4);
    float* dinv    = (float*)alloc((size_t)N_NODES * 4);
    int*   count   = (int*)alloc((size_t)N_NODES * 4);
    int*   offsets = (int*)alloc((size_t)N_NODES * 4);
    int*   cursor  = (int*)alloc((size_t)N_NODES * 4);
    int*   bsum    = (int*)alloc(1024);
    int*   queue   = (int*)alloc(256);
    int*   csr_col = (int*)alloc((size_t)(N_EDGES + 128) * 4); // +128 pad for over-read
    // featS (N x 64) overlays B1: dead before GEMM1 writes B1.
    float* featS   = B1;

    const int eb = (N_EDGES + 255) / 256;
    const int rb128 = (N_NODES + 127) / 128; // 391
    const int rb64  = (N_NODES + 63) / 64;   // 782
    const int agg_grid = N_NODES / 4;        // 12500 (one node per wave)
    const int aggx_grid = 8 * 3125;          // 25000 blocks = total chunks

    // CSR build (every call — no cached state allowed)
    k_zero_i32<<<(N_NODES + 255) / 256, 256, 0, stream>>>(count, N_NODES);
    k_count<<<eb, 256, 0, stream>>>(row, count, csr_col + N_EDGES, queue);
    k_blocksum<<<SCAN_BLOCKS, 256, 0, stream>>>(count, bsum);
    k_scan_bsum<<<1, 256, 0, stream>>>(bsum);
    k_scan_final<<<SCAN_BLOCKS, 256, 0, stream>>>(count, bsum, offsets, cursor, dinv);
    k_scatter<<<eb, 256, 0, stream>>>(row, col, cursor, csr_col);

    // features pre-scaled by dinv (so aggregate gathers need no dinv[c])
    k_prescale64<<<(N_NODES * 16 + 255) / 256, 256, 0, stream>>>(feat, dinv, featS);

    // Layer 1: agg1 = A_hat@feat (F=64), then x1' = dinv .* relu(agg1@W1+b1)
    k_agg64<false><<<agg_grid, 256, 0, stream>>>(featS, B0, csr_col, offsets, count, dinv, nullptr);
    k_gemm<64, 128, 128, true, true, true><<<rb128 * 2, 256, 0, stream>>>(B0, W1, b1, dinv, B1, N_NODES);

    // Layer 2: agg2 = A_hat@x1 (F=128, XCD-queue panel kernel), then GEMM
    k_aggx<<<aggx_grid, 256, 0, stream>>>(B1, B0, csr_col, offsets, count, dinv, queue);
    k_gemm<128, 128, 128, true, true, false><<<rb128 * 2, 256, 0, stream>>>(B0, W2, b2, dinv, B1, N_NODES);

    // Layer 3: h3' = dinv .* (x2@W3), then out = A_hat-agg + b3
    k_gemm<128, 64, 64, false, false, true><<<rb64, 256, 0, stream>>>(B1, W3, nullptr, dinv, B0, N_NODES);
    k_agg64<true><<<agg_grid, 256, 0, stream>>>(B0, out, csr_col, offsets, count, dinv, b3);
}

// Round 12
// 305.567 us; speedup vs baseline: 1.8330x; 1.8330x over previous
//
#include <hip/hip_runtime.h>

#define N_NODES 50000
#define N_EDGES 800000

#define SCAN_CHUNK 256
#define SCAN_BLOCKS ((N_NODES + SCAN_CHUNK - 1) / SCAN_CHUNK) // 196

static inline size_t alignUp(size_t x, size_t a) { return (x + a - 1) & ~(a - 1); }

// ---------------- CSR build ----------------

__global__ void k_zero_i32(int* __restrict__ p, int n) {
    int i = blockIdx.x * 256 + threadIdx.x;
    if (i < n) p[i] = 0;
}

// count degrees; first 64 threads also zero the csr_col over-read pad
__global__ void k_count(const int* __restrict__ row, int* __restrict__ count,
                        int* __restrict__ pad) {
    int e = blockIdx.x * 256 + threadIdx.x;
    if (e < 64) pad[e] = 0;
    if (e < N_EDGES) atomicAdd(&count[row[e]], 1);
}

__global__ void k_blocksum(const int* __restrict__ count, int* __restrict__ bsum) {
    __shared__ int s[256];
    int t = threadIdx.x;
    int i = blockIdx.x * 256 + t;
    int v = (i < N_NODES) ? count[i] : 0;
    s[t] = v;
    __syncthreads();
    for (int off = 128; off > 0; off >>= 1) {
        if (t < off) s[t] += s[t + off];
        __syncthreads();
    }
    if (t == 0) bsum[blockIdx.x] = s[0];
}

__global__ void k_scan_bsum(int* __restrict__ bsum) {
    __shared__ int s[256];
    int t = threadIdx.x;
    int v = (t < SCAN_BLOCKS) ? bsum[t] : 0;
    s[t] = v;
    __syncthreads();
    for (int off = 1; off < 256; off <<= 1) {
        int add = (t >= off) ? s[t - off] : 0;
        __syncthreads();
        s[t] += add;
        __syncthreads();
    }
    if (t < SCAN_BLOCKS) bsum[t] = s[t] - v; // exclusive
}

__global__ void k_scan_final(const int* __restrict__ count, const int* __restrict__ bsum,
                             int* __restrict__ offsets, int* __restrict__ cursor,
                             float* __restrict__ dinv) {
    __shared__ int s[256];
    int t = threadIdx.x;
    int i = blockIdx.x * 256 + t;
    int v = (i < N_NODES) ? count[i] : 0;
    s[t] = v;
    __syncthreads();
    for (int off = 1; off < 256; off <<= 1) {
        int add = (t >= off) ? s[t - off] : 0;
        __syncthreads();
        s[t] += add;
        __syncthreads();
    }
    if (i < N_NODES) {
        int excl = s[t] - v + bsum[blockIdx.x];
        offsets[i] = excl;
        cursor[i]  = excl;
        dinv[i]    = rsqrtf((float)(v + 1)); // +1 self-loop; always > 0
    }
}

// scatter edges into CSR; fused: same thread index also prescales one float4
// of features (N_NODES*16 float4s == N_EDGES == 800000 — exact same grid).
__global__ void k_scatter(const int* __restrict__ row, const int* __restrict__ col,
                          int* __restrict__ cursor, int* __restrict__ csr_col,
                          const float* __restrict__ feat, const float* __restrict__ dinv,
                          float* __restrict__ featS) {
    int e = blockIdx.x * 256 + threadIdx.x;
    if (e < N_EDGES) {
        // prescale: featS[node,:] = dinv[node] * feat[node,:]
        int node = e >> 4;
        float d = dinv[node];
        float4 v = reinterpret_cast<const float4*>(feat)[e];
        reinterpret_cast<float4*>(featS)[e] =
            make_float4(v.x * d, v.y * d, v.z * d, v.w * d);
        // scatter
        int r = row[e];
        int pos = atomicAdd(&cursor[r], 1);
        csr_col[pos] = col[e];
    }
}

// ---------------- Aggregation over PRE-SCALED rows ----------------
// out[i] = dinv_i * ( h'[i] + sum_c h'[c] ) (+bias), h' = dinv .* h
// One node per WAVE; csr_col padded (+64 zeros) so over-read is safe.

// F=128 (R4-proven best): 64 lanes x float2 = one 512B row per instruction;
// 8 edges per batch (8 gathers in flight).
template <bool BIAS>
__global__ __launch_bounds__(256) void k_agg128(const float* __restrict__ hs, float* __restrict__ out,
        const int* __restrict__ csr_col, const int* __restrict__ offsets,
        const int* __restrict__ count, const float* __restrict__ dinv,
        const float* __restrict__ bias) {
    int lane = threadIdx.x & 63;
    int node = blockIdx.x * 4 + (threadIdx.x >> 6);
    const float2* h2 = reinterpret_cast<const float2*>(hs);

    float ax[8], ay[8];
#pragma unroll
    for (int u = 0; u < 8; u++) { ax[u] = 0.f; ay[u] = 0.f; }

    int n = count[node];
    const int* cp = csr_col + offsets[node];

    int e = 0;
    for (; e + 8 <= n; e += 8) {
        int c[8];
#pragma unroll
        for (int u = 0; u < 8; u++) c[u] = cp[e + u];
#pragma unroll
        for (int u = 0; u < 8; u++) {
            float2 v = h2[(size_t)c[u] * 64 + lane];
            ax[u] += v.x; ay[u] += v.y;
        }
    }
    if (e < n) { // one predicated batch covers rem 1..7
        int c[8];
#pragma unroll
        for (int u = 0; u < 8; u++) c[u] = cp[e + u]; // padded, safe
#pragma unroll
        for (int u = 0; u < 8; u++) {
            float2 v = h2[(size_t)c[u] * 64 + lane];
            if (e + u < n) { ax[u] += v.x; ay[u] += v.y; }
        }
    }

    float sx = 0.f, sy = 0.f;
#pragma unroll
    for (int u = 0; u < 8; u++) { sx += ax[u]; sy += ay[u]; }
    float2 self = h2[(size_t)node * 64 + lane];
    float d = dinv[node];
    float ox = (sx + self.x) * d, oy = (sy + self.y) * d;
    if (BIAS) { ox += bias[2 * lane]; oy += bias[2 * lane + 1]; }
    reinterpret_cast<float2*>(out)[(size_t)node * 64 + lane] = make_float2(ox, oy);
}

// F=64 (R5-proven best): 16 lanes x float4 = one 256B row, 4 edges per
// instruction -> 32 edges per batch; scalar bounds via readfirstlane.
template <bool BIAS>
__global__ __launch_bounds__(256) void k_agg64(const float* __restrict__ hs, float* __restrict__ out,
        const int* __restrict__ csr_col, const int* __restrict__ offsets,
        const int* __restrict__ count, const float* __restrict__ dinv,
        const float* __restrict__ bias) {
    int lane = threadIdx.x & 63;
    int node = blockIdx.x * 4 + (threadIdx.x >> 6);
    int q = lane >> 4;        // edge sub-slot (0..3)
    int f4 = lane & 15;       // float4 index within 64-float row
    const char* base = (const char*)hs;
    uint32_t fo = (uint32_t)f4 << 4;

    int n = __builtin_amdgcn_readfirstlane(count[node]);
    int start = __builtin_amdgcn_readfirstlane(offsets[node]);
    const int* cp = csr_col + start;

    float4 a0 = make_float4(0.f, 0.f, 0.f, 0.f);
    float4 a1 = make_float4(0.f, 0.f, 0.f, 0.f);

    int e = 0;
    for (; e + 32 <= n; e += 32) {
        int c[8];
#pragma unroll
        for (int u = 0; u < 8; u++) c[u] = cp[e + 4 * u + q];
        float4 v[8];
#pragma unroll
        for (int u = 0; u < 8; u++)
            v[u] = *reinterpret_cast<const float4*>(base + (((uint32_t)c[u] << 8) + fo));
#pragma unroll
        for (int u = 0; u < 8; u += 2) {
            a0.x += v[u].x; a0.y += v[u].y; a0.z += v[u].z; a0.w += v[u].w;
            a1.x += v[u+1].x; a1.y += v[u+1].y; a1.z += v[u+1].z; a1.w += v[u+1].w;
        }
    }
    if (e < n) {
        int c[8];
#pragma unroll
        for (int u = 0; u < 8; u++) c[u] = cp[e + 4 * u + q]; // padded, safe
        float4 v[8];
#pragma unroll
        for (int u = 0; u < 8; u++)
            v[u] = *reinterpret_cast<const float4*>(base + (((uint32_t)c[u] << 8) + fo));
#pragma unroll
        for (int u = 0; u < 8; u++) {
            if (e + 4 * u + q < n) {
                a0.x += v[u].x; a0.y += v[u].y; a0.z += v[u].z; a0.w += v[u].w;
            }
        }
    }

    float sx = a0.x + a1.x, sy = a0.y + a1.y, sz = a0.z + a1.z, sw = a0.w + a1.w;
    sx += __shfl_xor(sx, 16); sy += __shfl_xor(sy, 16);
    sz += __shfl_xor(sz, 16); sw += __shfl_xor(sw, 16);
    sx += __shfl_xor(sx, 32); sy += __shfl_xor(sy, 32);
    sz += __shfl_xor(sz, 32); sw += __shfl_xor(sw, 32);
    if (q == 0) {
        float4 self = *reinterpret_cast<const float4*>(base + ((uint32_t)node << 8) + fo);
        float d = dinv[node];
        float ox = (sx + self.x) * d, oy = (sy + self.y) * d;
        float oz = (sz + self.z) * d, ow = (sw + self.w) * d;
        if (BIAS) {
            float4 bv = *reinterpret_cast<const float4*>(&bias[f4 * 4]);
            ox += bv.x; oy += bv.y; oz += bv.z; ow += bv.w;
        }
        *reinterpret_cast<float4*>((char*)out + ((uint32_t)node << 8) + fo) =
            make_float4(ox, oy, oz, ow);
    }
}

// ---------------- fp32 GEMM (R4 known-good: BK=32, BN=64) ----------------
// out[r,c] = post( x[r,:] @ W[:,c] ), post = (+bias) -> relu -> (*dinv[r])
// __launch_bounds__(256,4) caps VGPR at 128 (R3 spilled at 256 VGPR);
// '#pragma unroll 1' on the K-tile loop prevents whole-kernel flattening.
// RPT-dependent branches are `if constexpr` (R6 compile failure).

template <int K, int NOUT, int BM, bool RELU, bool BIAS, bool SCALE>
__global__ __launch_bounds__(256, 4) void k_gemm(const float* __restrict__ x,
        const float* __restrict__ W, const float* __restrict__ bias,
        const float* __restrict__ dinv, float* __restrict__ out, int nrows) {
    constexpr int BK = 32, BN = 64;
    constexpr int NCB = NOUT / BN;  // column blocks per row
    constexpr int RPT = BM / 16;    // rows per thread (8 or 4)
    __shared__ float xt[BK * BM];
    __shared__ float wt[BK * BN];

    int tid = threadIdx.x;
    int rg = tid & 15;  // row group
    int cg = tid >> 4;  // col group: cols cg*4..+3 of the 64-col strip
    int row0 = (blockIdx.x / NCB) * BM;
    int col0 = (blockIdx.x % NCB) * BN;

    float acc[RPT][4] = {};

#pragma unroll 1
    for (int kk = 0; kk < K; kk += BK) {
        __syncthreads();
        // ---- x tile: BM rows x 32 k, coalesced float4, swizzled transpose store
#pragma unroll
        for (int t = 0; t < BM / 32; ++t) {
            int idx = tid + t * 256;
            int r = idx >> 3;
            int kc = (idx & 7) * 4;
            float4 v = make_float4(0.f, 0.f, 0.f, 0.f);
            int gr = row0 + r;
            if (gr < nrows) v = *reinterpret_cast<const float4*>(&x[(size_t)gr * K + kk + kc]);
            int rc = r ^ kc; // kc in {0..28}: swizzle within 32-row stripe
            xt[(kc + 0) * BM + rc] = v.x;
            xt[(kc + 1) * BM + rc] = v.y;
            xt[(kc + 2) * BM + rc] = v.z;
            xt[(kc + 3) * BM + rc] = v.w;
        }
        // ---- W tile: 32 k x 64 n
#pragma unroll
        for (int t = 0; t < 2; ++t) {
            int idx = tid + t * 256;
            int k = idx >> 4;
            int c = (idx & 15) * 4;
            *reinterpret_cast<float4*>(&wt[k * BN + c]) =
                *reinterpret_cast<const float4*>(&W[(size_t)(kk + k) * NOUT + col0 + c]);
        }
        __syncthreads();

#pragma unroll
        for (int k = 0; k < BK; ++k) {
            int s = k & 28;
            float4 wv = *reinterpret_cast<const float4*>(&wt[k * BN + cg * 4]);
            float wr[4] = {wv.x, wv.y, wv.z, wv.w};
            float xr[RPT];
            float4 x0 = *reinterpret_cast<const float4*>(&xt[k * BM + ((rg * 4) ^ s)]);
            xr[0] = x0.x; xr[1] = x0.y; xr[2] = x0.z; xr[3] = x0.w;
            if constexpr (RPT == 8) {
                float4 x1 = *reinterpret_cast<const float4*>(&xt[k * BM + (((rg * 4) ^ s) + 64)]);
                xr[4] = x1.x; xr[5] = x1.y; xr[6] = x1.z; xr[7] = x1.w;
            }
#pragma unroll
            for (int a = 0; a < RPT; a++)
#pragma unroll
                for (int b = 0; b < 4; b++) acc[a][b] += xr[a] * wr[b];
        }
    }

    float bv[4];
    if (BIAS) {
#pragma unroll
        for (int b = 0; b < 4; b++) bv[b] = bias[col0 + cg * 4 + b];
    }
#pragma unroll
    for (int a = 0; a < RPT; a++) {
        int r = rg * 4 + (a & 3) + ((a >= 4) ? 64 : 0);
        int gr = row0 + r;
        if (gr >= nrows) continue;
        float d = SCALE ? dinv[gr] : 1.f;
        float o[4];
#pragma unroll
        for (int b = 0; b < 4; b++) {
            float v = acc[a][b];
            if (BIAS) v += bv[b];
            if (RELU) v = fmaxf(v, 0.f);
            o[b] = v * d;
        }
        *reinterpret_cast<float4*>(&out[(size_t)gr * NOUT + col0 + cg * 4]) =
            make_float4(o[0], o[1], o[2], o[3]);
    }
}

// ---------------- launch ----------------

extern "C" void kernel_launch(void* const* d_in, const int* in_sizes, int n_in,
                              void* d_out, int out_size, void* d_ws, size_t ws_size,
                              hipStream_t stream) {
    const float* feat = (const float*)d_in[0]; // [N, 64]
    const float* W1 = (const float*)d_in[1];   // [64, 128]
    const float* b1 = (const float*)d_in[2];
    const float* W2 = (const float*)d_in[3];   // [128, 128]
    const float* b2 = (const float*)d_in[4];
    const float* W3 = (const float*)d_in[5];   // [128, 64]
    const float* b3 = (const float*)d_in[6];
    const int* ei = (const int*)d_in[7];       // [2, E]
    const int* row = ei;
    const int* col = ei + N_EDGES;
    float* out = (float*)d_out;

    // workspace bump allocator (256B aligned)
    char* ws = (char*)d_ws;
    size_t off = 0;
    auto alloc = [&](size_t bytes) {
        void* p = ws + off;
        off = alignUp(off + bytes, 256);
        return p;
    };
    float* B0      = (float*)alloc((size_t)N_NODES * 128 * 4);
    float* B1      = (float*)alloc((size_t)N_NODES * 128 * 4);
    float* dinv    = (float*)alloc((size_t)N_NODES * 4);
    int*   count   = (int*)alloc((size_t)N_NODES * 4);
    int*   offsets = (int*)alloc((size_t)N_NODES * 4);
    int*   cursor  = (int*)alloc((size_t)N_NODES * 4);
    int*   bsum    = (int*)alloc(1024);
    int*   csr_col = (int*)alloc((size_t)(N_EDGES + 64) * 4); // +64 pad for over-read
    // featS (N x 64) overlays B1: dead before GEMM1 writes B1.
    float* featS   = B1;

    const int eb = (N_EDGES + 255) / 256; // 3125
    const int rb128 = (N_NODES + 127) / 128; // 391
    const int rb64  = (N_NODES + 63) / 64;   // 782
    const int agg_grid = N_NODES / 4;        // 12500 (one node per wave)

    // CSR build (every call — no cached state allowed)
    k_zero_i32<<<(N_NODES + 255) / 256, 256, 0, stream>>>(count, N_NODES);
    k_count<<<eb, 256, 0, stream>>>(row, count, csr_col + N_EDGES);
    k_blocksum<<<SCAN_BLOCKS, 256, 0, stream>>>(count, bsum);
    k_scan_bsum<<<1, 256, 0, stream>>>(bsum);
    k_scan_final<<<SCAN_BLOCKS, 256, 0, stream>>>(count, bsum, offsets, cursor, dinv);
    // scatter + fused feature prescale (same 800000-thread grid)
    k_scatter<<<eb, 256, 0, stream>>>(row, col, cursor, csr_col, feat, dinv, featS);

    // Layer 1: agg1 = A_hat@feat (F=64), then x1' = dinv .* relu(agg1@W1+b1)
    k_agg64<false><<<agg_grid, 256, 0, stream>>>(featS, B0, csr_col, offsets, count, dinv, nullptr);
    k_gemm<64, 128, 128, true, true, true><<<rb128 * 2, 256, 0, stream>>>(B0, W1, b1, dinv, B1, N_NODES);

    // Layer 2: agg2 = A_hat@x1 (F=128), then x2 = relu(agg2@W2+b2) (unscaled)
    k_agg128<false><<<agg_grid, 256, 0, stream>>>(B1, B0, csr_col, offsets, count, dinv, nullptr);
    k_gemm<128, 128, 128, true, true, false><<<rb128 * 2, 256, 0, stream>>>(B0, W2, b2, dinv, B1, N_NODES);

    // Layer 3: h3' = dinv .* (x2@W3), then out = A_hat-agg + b3
    k_gemm<128, 64, 64, false, false, true><<<rb64, 256, 0, stream>>>(B1, W3, nullptr, dinv, B0, N_NODES);
    k_agg64<true><<<agg_grid, 256, 0, stream>>>(B0, out, csr_col, offsets, count, dinv, b3);
}

// Round 13
// 303.681 us; speedup vs baseline: 1.8444x; 1.0062x over previous
//
#include <hip/hip_runtime.h>

#define N_NODES 50000
#define N_EDGES 800000

#define SCAN_CHUNK 256
#define SCAN_BLOCKS ((N_NODES + SCAN_CHUNK - 1) / SCAN_CHUNK) // 196

static inline size_t alignUp(size_t x, size_t a) { return (x + a - 1) & ~(a - 1); }

// ---------------- CSR build ----------------
// R13: atomic counters padded to ONE PER 64B CACHELINE (stride 16 ints).
// R12 profile: k_scatter 62us @ VALUBusy 0.5% — 16 counters/line x deg 16
// = ~256 serialized same-line atomics. Padded buffers overlay dead B0.

__global__ void k_zero_i32(int* __restrict__ p, int n) {
    int i = blockIdx.x * 256 + threadIdx.x;
    if (i < n) p[i] = 0;
}

// count degrees into PADDED counters; first 64 threads zero csr_col pad
__global__ void k_count(const int* __restrict__ row, int* __restrict__ count_p,
                        int* __restrict__ pad) {
    int e = blockIdx.x * 256 + threadIdx.x;
    if (e < 64) pad[e] = 0;
    if (e < N_EDGES) atomicAdd(&count_p[row[e] << 4], 1);
}

__global__ void k_blocksum(const int* __restrict__ count_p, int* __restrict__ bsum) {
    __shared__ int s[256];
    int t = threadIdx.x;
    int i = blockIdx.x * 256 + t;
    int v = (i < N_NODES) ? count_p[i << 4] : 0;
    s[t] = v;
    __syncthreads();
    for (int off = 128; off > 0; off >>= 1) {
        if (t < off) s[t] += s[t + off];
        __syncthreads();
    }
    if (t == 0) bsum[blockIdx.x] = s[0];
}

__global__ void k_scan_bsum(int* __restrict__ bsum) {
    __shared__ int s[256];
    int t = threadIdx.x;
    int v = (t < SCAN_BLOCKS) ? bsum[t] : 0;
    s[t] = v;
    __syncthreads();
    for (int off = 1; off < 256; off <<= 1) {
        int add = (t >= off) ? s[t - off] : 0;
        __syncthreads();
        s[t] += add;
        __syncthreads();
    }
    if (t < SCAN_BLOCKS) bsum[t] = s[t] - v; // exclusive
}

// reads padded counts; writes compact count/offsets (for aggs), padded cursor
__global__ void k_scan_final(const int* __restrict__ count_p, const int* __restrict__ bsum,
                             int* __restrict__ countc, int* __restrict__ offsets,
                             int* __restrict__ cursor_p, float* __restrict__ dinv) {
    __shared__ int s[256];
    int t = threadIdx.x;
    int i = blockIdx.x * 256 + t;
    int v = (i < N_NODES) ? count_p[i << 4] : 0;
    s[t] = v;
    __syncthreads();
    for (int off = 1; off < 256; off <<= 1) {
        int add = (t >= off) ? s[t - off] : 0;
        __syncthreads();
        s[t] += add;
        __syncthreads();
    }
    if (i < N_NODES) {
        int excl = s[t] - v + bsum[blockIdx.x];
        countc[i]         = v;
        offsets[i]        = excl;
        cursor_p[i << 4]  = excl;
        dinv[i]           = rsqrtf((float)(v + 1)); // +1 self-loop; always > 0
    }
}

// scatter edges into CSR (padded cursor); fused: same thread also prescales
// one float4 of features (N_NODES*16 float4s == N_EDGES == 800000).
__global__ void k_scatter(const int* __restrict__ row, const int* __restrict__ col,
                          int* __restrict__ cursor_p, int* __restrict__ csr_col,
                          const float* __restrict__ feat, const float* __restrict__ dinv,
                          float* __restrict__ featS) {
    int e = blockIdx.x * 256 + threadIdx.x;
    if (e < N_EDGES) {
        // prescale: featS[node,:] = dinv[node] * feat[node,:]
        int node = e >> 4;
        float d = dinv[node];
        float4 v = reinterpret_cast<const float4*>(feat)[e];
        reinterpret_cast<float4*>(featS)[e] =
            make_float4(v.x * d, v.y * d, v.z * d, v.w * d);
        // scatter
        int r = row[e];
        int pos = atomicAdd(&cursor_p[r << 4], 1);
        csr_col[pos] = col[e];
    }
}

// ---------------- Aggregation over PRE-SCALED rows ----------------
// out[i] = dinv_i * ( h'[i] + sum_c h'[c] ) (+bias), h' = dinv .* h
// One node per WAVE; csr_col padded (+64 zeros) so over-read is safe.

// F=128 (R4-proven best): 64 lanes x float2 = one 512B row per instruction;
// 8 edges per batch (8 gathers in flight).
template <bool BIAS>
__global__ __launch_bounds__(256) void k_agg128(const float* __restrict__ hs, float* __restrict__ out,
        const int* __restrict__ csr_col, const int* __restrict__ offsets,
        const int* __restrict__ count, const float* __restrict__ dinv,
        const float* __restrict__ bias) {
    int lane = threadIdx.x & 63;
    int node = blockIdx.x * 4 + (threadIdx.x >> 6);
    const float2* h2 = reinterpret_cast<const float2*>(hs);

    float ax[8], ay[8];
#pragma unroll
    for (int u = 0; u < 8; u++) { ax[u] = 0.f; ay[u] = 0.f; }

    int n = count[node];
    const int* cp = csr_col + offsets[node];

    int e = 0;
    for (; e + 8 <= n; e += 8) {
        int c[8];
#pragma unroll
        for (int u = 0; u < 8; u++) c[u] = cp[e + u];
#pragma unroll
        for (int u = 0; u < 8; u++) {
            float2 v = h2[(size_t)c[u] * 64 + lane];
            ax[u] += v.x; ay[u] += v.y;
        }
    }
    if (e < n) { // one predicated batch covers rem 1..7
        int c[8];
#pragma unroll
        for (int u = 0; u < 8; u++) c[u] = cp[e + u]; // padded, safe
#pragma unroll
        for (int u = 0; u < 8; u++) {
            float2 v = h2[(size_t)c[u] * 64 + lane];
            if (e + u < n) { ax[u] += v.x; ay[u] += v.y; }
        }
    }

    float sx = 0.f, sy = 0.f;
#pragma unroll
    for (int u = 0; u < 8; u++) { sx += ax[u]; sy += ay[u]; }
    float2 self = h2[(size_t)node * 64 + lane];
    float d = dinv[node];
    float ox = (sx + self.x) * d, oy = (sy + self.y) * d;
    if (BIAS) { ox += bias[2 * lane]; oy += bias[2 * lane + 1]; }
    reinterpret_cast<float2*>(out)[(size_t)node * 64 + lane] = make_float2(ox, oy);
}

// F=64 (R5-proven best): 16 lanes x float4 = one 256B row, 4 edges per
// instruction -> 32 edges per batch; scalar bounds via readfirstlane.
template <bool BIAS>
__global__ __launch_bounds__(256) void k_agg64(const float* __restrict__ hs, float* __restrict__ out,
        const int* __restrict__ csr_col, const int* __restrict__ offsets,
        const int* __restrict__ count, const float* __restrict__ dinv,
        const float* __restrict__ bias) {
    int lane = threadIdx.x & 63;
    int node = blockIdx.x * 4 + (threadIdx.x >> 6);
    int q = lane >> 4;        // edge sub-slot (0..3)
    int f4 = lane & 15;       // float4 index within 64-float row
    const char* base = (const char*)hs;
    uint32_t fo = (uint32_t)f4 << 4;

    int n = __builtin_amdgcn_readfirstlane(count[node]);
    int start = __builtin_amdgcn_readfirstlane(offsets[node]);
    const int* cp = csr_col + start;

    float4 a0 = make_float4(0.f, 0.f, 0.f, 0.f);
    float4 a1 = make_float4(0.f, 0.f, 0.f, 0.f);

    int e = 0;
    for (; e + 32 <= n; e += 32) {
        int c[8];
#pragma unroll
        for (int u = 0; u < 8; u++) c[u] = cp[e + 4 * u + q];
        float4 v[8];
#pragma unroll
        for (int u = 0; u < 8; u++)
            v[u] = *reinterpret_cast<const float4*>(base + (((uint32_t)c[u] << 8) + fo));
#pragma unroll
        for (int u = 0; u < 8; u += 2) {
            a0.x += v[u].x; a0.y += v[u].y; a0.z += v[u].z; a0.w += v[u].w;
            a1.x += v[u+1].x; a1.y += v[u+1].y; a1.z += v[u+1].z; a1.w += v[u+1].w;
        }
    }
    if (e < n) {
        int c[8];
#pragma unroll
        for (int u = 0; u < 8; u++) c[u] = cp[e + 4 * u + q]; // padded, safe
        float4 v[8];
#pragma unroll
        for (int u = 0; u < 8; u++)
            v[u] = *reinterpret_cast<const float4*>(base + (((uint32_t)c[u] << 8) + fo));
#pragma unroll
        for (int u = 0; u < 8; u++) {
            if (e + 4 * u + q < n) {
                a0.x += v[u].x; a0.y += v[u].y; a0.z += v[u].z; a0.w += v[u].w;
            }
        }
    }

    float sx = a0.x + a1.x, sy = a0.y + a1.y, sz = a0.z + a1.z, sw = a0.w + a1.w;
    sx += __shfl_xor(sx, 16); sy += __shfl_xor(sy, 16);
    sz += __shfl_xor(sz, 16); sw += __shfl_xor(sw, 16);
    sx += __shfl_xor(sx, 32); sy += __shfl_xor(sy, 32);
    sz += __shfl_xor(sz, 32); sw += __shfl_xor(sw, 32);
    if (q == 0) {
        float4 self = *reinterpret_cast<const float4*>(base + ((uint32_t)node << 8) + fo);
        float d = dinv[node];
        float ox = (sx + self.x) * d, oy = (sy + self.y) * d;
        float oz = (sz + self.z) * d, ow = (sw + self.w) * d;
        if (BIAS) {
            float4 bv = *reinterpret_cast<const float4*>(&bias[f4 * 4]);
            ox += bv.x; oy += bv.y; oz += bv.z; ow += bv.w;
        }
        *reinterpret_cast<float4*>((char*)out + ((uint32_t)node << 8) + fo) =
            make_float4(ox, oy, oz, ow);
    }
}

// ---------------- fp32 GEMM (R4 known-good: BK=32, BN=64) ----------------
// out[r,c] = post( x[r,:] @ W[:,c] ), post = (+bias) -> relu -> (*dinv[r])
// __launch_bounds__(256,4) caps VGPR at 128 (R3 spilled at 256 VGPR);
// '#pragma unroll 1' on the K-tile loop prevents whole-kernel flattening.
// RPT-dependent branches are `if constexpr` (R6 compile failure).

template <int K, int NOUT, int BM, bool RELU, bool BIAS, bool SCALE>
__global__ __launch_bounds__(256, 4) void k_gemm(const float* __restrict__ x,
        const float* __restrict__ W, const float* __restrict__ bias,
        const float* __restrict__ dinv, float* __restrict__ out, int nrows) {
    constexpr int BK = 32, BN = 64;
    constexpr int NCB = NOUT / BN;  // column blocks per row
    constexpr int RPT = BM / 16;    // rows per thread (8 or 4)
    __shared__ float xt[BK * BM];
    __shared__ float wt[BK * BN];

    int tid = threadIdx.x;
    int rg = tid & 15;  // row group
    int cg = tid >> 4;  // col group: cols cg*4..+3 of the 64-col strip
    int row0 = (blockIdx.x / NCB) * BM;
    int col0 = (blockIdx.x % NCB) * BN;

    float acc[RPT][4] = {};

#pragma unroll 1
    for (int kk = 0; kk < K; kk += BK) {
        __syncthreads();
        // ---- x tile: BM rows x 32 k, coalesced float4, swizzled transpose store
#pragma unroll
        for (int t = 0; t < BM / 32; ++t) {
            int idx = tid + t * 256;
            int r = idx >> 3;
            int kc = (idx & 7) * 4;
            float4 v = make_float4(0.f, 0.f, 0.f, 0.f);
            int gr = row0 + r;
            if (gr < nrows) v = *reinterpret_cast<const float4*>(&x[(size_t)gr * K + kk + kc]);
            int rc = r ^ kc; // kc in {0..28}: swizzle within 32-row stripe
            xt[(kc + 0) * BM + rc] = v.x;
            xt[(kc + 1) * BM + rc] = v.y;
            xt[(kc + 2) * BM + rc] = v.z;
            xt[(kc + 3) * BM + rc] = v.w;
        }
        // ---- W tile: 32 k x 64 n
#pragma unroll
        for (int t = 0; t < 2; ++t) {
            int idx = tid + t * 256;
            int k = idx >> 4;
            int c = (idx & 15) * 4;
            *reinterpret_cast<float4*>(&wt[k * BN + c]) =
                *reinterpret_cast<const float4*>(&W[(size_t)(kk + k) * NOUT + col0 + c]);
        }
        __syncthreads();

#pragma unroll
        for (int k = 0; k < BK; ++k) {
            int s = k & 28;
            float4 wv = *reinterpret_cast<const float4*>(&wt[k * BN + cg * 4]);
            float wr[4] = {wv.x, wv.y, wv.z, wv.w};
            float xr[RPT];
            float4 x0 = *reinterpret_cast<const float4*>(&xt[k * BM + ((rg * 4) ^ s)]);
            xr[0] = x0.x; xr[1] = x0.y; xr[2] = x0.z; xr[3] = x0.w;
            if constexpr (RPT == 8) {
                float4 x1 = *reinterpret_cast<const float4*>(&xt[k * BM + (((rg * 4) ^ s) + 64)]);
                xr[4] = x1.x; xr[5] = x1.y; xr[6] = x1.z; xr[7] = x1.w;
            }
#pragma unroll
            for (int a = 0; a < RPT; a++)
#pragma unroll
                for (int b = 0; b < 4; b++) acc[a][b] += xr[a] * wr[b];
        }
    }

    float bv[4];
    if (BIAS) {
#pragma unroll
        for (int b = 0; b < 4; b++) bv[b] = bias[col0 + cg * 4 + b];
    }
#pragma unroll
    for (int a = 0; a < RPT; a++) {
        int r = rg * 4 + (a & 3) + ((a >= 4) ? 64 : 0);
        int gr = row0 + r;
        if (gr >= nrows) continue;
        float d = SCALE ? dinv[gr] : 1.f;
        float o[4];
#pragma unroll
        for (int b = 0; b < 4; b++) {
            float v = acc[a][b];
            if (BIAS) v += bv[b];
            if (RELU) v = fmaxf(v, 0.f);
            o[b] = v * d;
        }
        *reinterpret_cast<float4*>(&out[(size_t)gr * NOUT + col0 + cg * 4]) =
            make_float4(o[0], o[1], o[2], o[3]);
    }
}

// ---------------- launch ----------------

extern "C" void kernel_launch(void* const* d_in, const int* in_sizes, int n_in,
                              void* d_out, int out_size, void* d_ws, size_t ws_size,
                              hipStream_t stream) {
    const float* feat = (const float*)d_in[0]; // [N, 64]
    const float* W1 = (const float*)d_in[1];   // [64, 128]
    const float* b1 = (const float*)d_in[2];
    const float* W2 = (const float*)d_in[3];   // [128, 128]
    const float* b2 = (const float*)d_in[4];
    const float* W3 = (const float*)d_in[5];   // [128, 64]
    const float* b3 = (const float*)d_in[6];
    const int* ei = (const int*)d_in[7];       // [2, E]
    const int* row = ei;
    const int* col = ei + N_EDGES;
    float* out = (float*)d_out;

    // workspace bump allocator (256B aligned)
    char* ws = (char*)d_ws;
    size_t off = 0;
    auto alloc = [&](size_t bytes) {
        void* p = ws + off;
        off = alignUp(off + bytes, 256);
        return p;
    };
    float* B0      = (float*)alloc((size_t)N_NODES * 128 * 4);
    float* B1      = (float*)alloc((size_t)N_NODES * 128 * 4);
    float* dinv    = (float*)alloc((size_t)N_NODES * 4);
    int*   countc  = (int*)alloc((size_t)N_NODES * 4);
    int*   offsets = (int*)alloc((size_t)N_NODES * 4);
    int*   bsum    = (int*)alloc(1024);
    int*   csr_col = (int*)alloc((size_t)(N_EDGES + 64) * 4); // +64 pad for over-read
    // Padded (1 counter / 64B line) atomic buffers overlay B0: dead until
    // the first aggregation writes B0 (after scatter). 2 x 800000 ints.
    int* count_p  = (int*)B0;
    int* cursor_p = count_p + 800000;
    // featS (N x 64) overlays B1: dead before GEMM1 writes B1.
    float* featS   = B1;

    const int eb = (N_EDGES + 255) / 256; // 3125
    const int rb128 = (N_NODES + 127) / 128; // 391
    const int rb64  = (N_NODES + 63) / 64;   // 782
    const int agg_grid = N_NODES / 4;        // 12500 (one node per wave)

    // CSR build (every call — no cached state allowed)
    k_zero_i32<<<eb, 256, 0, stream>>>(count_p, 800000); // zero padded counters
    k_count<<<eb, 256, 0, stream>>>(row, count_p, csr_col + N_EDGES);
    k_blocksum<<<SCAN_BLOCKS, 256, 0, stream>>>(count_p, bsum);
    k_scan_bsum<<<1, 256, 0, stream>>>(bsum);
    k_scan_final<<<SCAN_BLOCKS, 256, 0, stream>>>(count_p, bsum, countc, offsets, cursor_p, dinv);
    // scatter + fused feature prescale (same 800000-thread grid)
    k_scatter<<<eb, 256, 0, stream>>>(row, col, cursor_p, csr_col, feat, dinv, featS);

    // Layer 1: agg1 = A_hat@feat (F=64), then x1' = dinv .* relu(agg1@W1+b1)
    k_agg64<false><<<agg_grid, 256, 0, stream>>>(featS, B0, csr_col, offsets, countc, dinv, nullptr);
    k_gemm<64, 128, 128, true, true, true><<<rb128 * 2, 256, 0, stream>>>(B0, W1, b1, dinv, B1, N_NODES);

    // Layer 2: agg2 = A_hat@x1 (F=128), then x2 = relu(agg2@W2+b2) (unscaled)
    k_agg128<false><<<agg_grid, 256, 0, stream>>>(B1, B0, csr_col, offsets, countc, dinv, nullptr);
    k_gemm<128, 128, 128, true, true, false><<<rb128 * 2, 256, 0, stream>>>(B0, W2, b2, dinv, B1, N_NODES);

    // Layer 3: h3' = dinv .* (x2@W3), then out = A_hat-agg + b3
    k_gemm<128, 64, 64, false, false, true><<<rb64, 256, 0, stream>>>(B1, W3, nullptr, dinv, B0, N_NODES);
    k_agg64<true><<<agg_grid, 256, 0, stream>>>(B0, out, csr_col, offsets, countc, dinv, b3);
}

// Round 14
// 262.336 us; speedup vs baseline: 2.1351x; 1.1576x over previous
//
#include <hip/hip_runtime.h>

#define N_NODES 50000
#define N_EDGES 800000

#define SCAN_CHUNK 256
#define SCAN_BLOCKS ((N_NODES + SCAN_CHUNK - 1) / SCAN_CHUNK) // 196

static inline size_t alignUp(size_t x, size_t a) { return (x + a - 1) & ~(a - 1); }

// ---------------- CSR build ----------------
// R14: rank-split build. Pass 1 (k_count) does the atomics AND saves each
// edge's intra-node rank (the atomic's return value, stored coalesced).
// Pass 2 (k_scatter) is atomic-free: pos = offsets[row] + rank — the random
// store no longer waits on an atomic round trip (R13: padding counters was
// null -> the bound was the atomic->store dependency, not line contention).

__global__ void k_zero_i32(int* __restrict__ p, int n) {
    int i = blockIdx.x * 256 + threadIdx.x;
    if (i < n) p[i] = 0;
}

// count degrees + save per-edge rank; first 64 threads zero csr_col pad
__global__ void k_count(const int* __restrict__ row, int* __restrict__ count,
                        int* __restrict__ rank, int* __restrict__ pad) {
    int e = blockIdx.x * 256 + threadIdx.x;
    if (e < 64) pad[e] = 0;
    if (e < N_EDGES) rank[e] = atomicAdd(&count[row[e]], 1);
}

__global__ void k_blocksum(const int* __restrict__ count, int* __restrict__ bsum) {
    __shared__ int s[256];
    int t = threadIdx.x;
    int i = blockIdx.x * 256 + t;
    int v = (i < N_NODES) ? count[i] : 0;
    s[t] = v;
    __syncthreads();
    for (int off = 128; off > 0; off >>= 1) {
        if (t < off) s[t] += s[t + off];
        __syncthreads();
    }
    if (t == 0) bsum[blockIdx.x] = s[0];
}

__global__ void k_scan_bsum(int* __restrict__ bsum) {
    __shared__ int s[256];
    int t = threadIdx.x;
    int v = (t < SCAN_BLOCKS) ? bsum[t] : 0;
    s[t] = v;
    __syncthreads();
    for (int off = 1; off < 256; off <<= 1) {
        int add = (t >= off) ? s[t - off] : 0;
        __syncthreads();
        s[t] += add;
        __syncthreads();
    }
    if (t < SCAN_BLOCKS) bsum[t] = s[t] - v; // exclusive
}

__global__ void k_scan_final(const int* __restrict__ count, const int* __restrict__ bsum,
                             int* __restrict__ offsets, float* __restrict__ dinv) {
    __shared__ int s[256];
    int t = threadIdx.x;
    int i = blockIdx.x * 256 + t;
    int v = (i < N_NODES) ? count[i] : 0;
    s[t] = v;
    __syncthreads();
    for (int off = 1; off < 256; off <<= 1) {
        int add = (t >= off) ? s[t - off] : 0;
        __syncthreads();
        s[t] += add;
        __syncthreads();
    }
    if (i < N_NODES) {
        offsets[i] = s[t] - v + bsum[blockIdx.x];
        dinv[i]    = rsqrtf((float)(v + 1)); // +1 self-loop; always > 0
    }
}

// atomic-free scatter: pos = offsets[row] + rank. Fused feature prescale
// (N_NODES*16 float4s == N_EDGES == 800000 — same grid).
__global__ void k_scatter(const int* __restrict__ row, const int* __restrict__ col,
                          const int* __restrict__ offsets, const int* __restrict__ rank,
                          int* __restrict__ csr_col,
                          const float* __restrict__ feat, const float* __restrict__ dinv,
                          float* __restrict__ featS) {
    int e = blockIdx.x * 256 + threadIdx.x;
    if (e < N_EDGES) {
        // prescale: featS[node,:] = dinv[node] * feat[node,:]
        int node = e >> 4;
        float d = dinv[node];
        float4 v = reinterpret_cast<const float4*>(feat)[e];
        reinterpret_cast<float4*>(featS)[e] =
            make_float4(v.x * d, v.y * d, v.z * d, v.w * d);
        // scatter (no atomic: rank precomputed in k_count)
        int r = row[e];
        csr_col[offsets[r] + rank[e]] = col[e];
    }
}

// ---------------- Aggregation over PRE-SCALED rows ----------------
// out[i] = dinv_i * ( h'[i] + sum_c h'[c] ) (+bias), h' = dinv .* h
// One node per WAVE; csr_col padded (+64 zeros) so over-read is safe.

// F=128 (R4-proven best): 64 lanes x float2 = one 512B row per instruction;
// 8 edges per batch (8 gathers in flight).
template <bool BIAS>
__global__ __launch_bounds__(256) void k_agg128(const float* __restrict__ hs, float* __restrict__ out,
        const int* __restrict__ csr_col, const int* __restrict__ offsets,
        const int* __restrict__ count, const float* __restrict__ dinv,
        const float* __restrict__ bias) {
    int lane = threadIdx.x & 63;
    int node = blockIdx.x * 4 + (threadIdx.x >> 6);
    const float2* h2 = reinterpret_cast<const float2*>(hs);

    float ax[8], ay[8];
#pragma unroll
    for (int u = 0; u < 8; u++) { ax[u] = 0.f; ay[u] = 0.f; }

    int n = count[node];
    const int* cp = csr_col + offsets[node];

    int e = 0;
    for (; e + 8 <= n; e += 8) {
        int c[8];
#pragma unroll
        for (int u = 0; u < 8; u++) c[u] = cp[e + u];
#pragma unroll
        for (int u = 0; u < 8; u++) {
            float2 v = h2[(size_t)c[u] * 64 + lane];
            ax[u] += v.x; ay[u] += v.y;
        }
    }
    if (e < n) { // one predicated batch covers rem 1..7
        int c[8];
#pragma unroll
        for (int u = 0; u < 8; u++) c[u] = cp[e + u]; // padded, safe
#pragma unroll
        for (int u = 0; u < 8; u++) {
            float2 v = h2[(size_t)c[u] * 64 + lane];
            if (e + u < n) { ax[u] += v.x; ay[u] += v.y; }
        }
    }

    float sx = 0.f, sy = 0.f;
#pragma unroll
    for (int u = 0; u < 8; u++) { sx += ax[u]; sy += ay[u]; }
    float2 self = h2[(size_t)node * 64 + lane];
    float d = dinv[node];
    float ox = (sx + self.x) * d, oy = (sy + self.y) * d;
    if (BIAS) { ox += bias[2 * lane]; oy += bias[2 * lane + 1]; }
    reinterpret_cast<float2*>(out)[(size_t)node * 64 + lane] = make_float2(ox, oy);
}

// F=64 (R5-proven best): 16 lanes x float4 = one 256B row, 4 edges per
// instruction -> 32 edges per batch; scalar bounds via readfirstlane.
template <bool BIAS>
__global__ __launch_bounds__(256) void k_agg64(const float* __restrict__ hs, float* __restrict__ out,
        const int* __restrict__ csr_col, const int* __restrict__ offsets,
        const int* __restrict__ count, const float* __restrict__ dinv,
        const float* __restrict__ bias) {
    int lane = threadIdx.x & 63;
    int node = blockIdx.x * 4 + (threadIdx.x >> 6);
    int q = lane >> 4;        // edge sub-slot (0..3)
    int f4 = lane & 15;       // float4 index within 64-float row
    const char* base = (const char*)hs;
    uint32_t fo = (uint32_t)f4 << 4;

    int n = __builtin_amdgcn_readfirstlane(count[node]);
    int start = __builtin_amdgcn_readfirstlane(offsets[node]);
    const int* cp = csr_col + start;

    float4 a0 = make_float4(0.f, 0.f, 0.f, 0.f);
    float4 a1 = make_float4(0.f, 0.f, 0.f, 0.f);

    int e = 0;
    for (; e + 32 <= n; e += 32) {
        int c[8];
#pragma unroll
        for (int u = 0; u < 8; u++) c[u] = cp[e + 4 * u + q];
        float4 v[8];
#pragma unroll
        for (int u = 0; u < 8; u++)
            v[u] = *reinterpret_cast<const float4*>(base + (((uint32_t)c[u] << 8) + fo));
#pragma unroll
        for (int u = 0; u < 8; u += 2) {
            a0.x += v[u].x; a0.y += v[u].y; a0.z += v[u].z; a0.w += v[u].w;
            a1.x += v[u+1].x; a1.y += v[u+1].y; a1.z += v[u+1].z; a1.w += v[u+1].w;
        }
    }
    if (e < n) {
        int c[8];
#pragma unroll
        for (int u = 0; u < 8; u++) c[u] = cp[e + 4 * u + q]; // padded, safe
        float4 v[8];
#pragma unroll
        for (int u = 0; u < 8; u++)
            v[u] = *reinterpret_cast<const float4*>(base + (((uint32_t)c[u] << 8) + fo));
#pragma unroll
        for (int u = 0; u < 8; u++) {
            if (e + 4 * u + q < n) {
                a0.x += v[u].x; a0.y += v[u].y; a0.z += v[u].z; a0.w += v[u].w;
            }
        }
    }

    float sx = a0.x + a1.x, sy = a0.y + a1.y, sz = a0.z + a1.z, sw = a0.w + a1.w;
    sx += __shfl_xor(sx, 16); sy += __shfl_xor(sy, 16);
    sz += __shfl_xor(sz, 16); sw += __shfl_xor(sw, 16);
    sx += __shfl_xor(sx, 32); sy += __shfl_xor(sy, 32);
    sz += __shfl_xor(sz, 32); sw += __shfl_xor(sw, 32);
    if (q == 0) {
        float4 self = *reinterpret_cast<const float4*>(base + ((uint32_t)node << 8) + fo);
        float d = dinv[node];
        float ox = (sx + self.x) * d, oy = (sy + self.y) * d;
        float oz = (sz + self.z) * d, ow = (sw + self.w) * d;
        if (BIAS) {
            float4 bv = *reinterpret_cast<const float4*>(&bias[f4 * 4]);
            ox += bv.x; oy += bv.y; oz += bv.z; ow += bv.w;
        }
        *reinterpret_cast<float4*>((char*)out + ((uint32_t)node << 8) + fo) =
            make_float4(ox, oy, oz, ow);
    }
}

// ---------------- fp32 GEMM (R4 known-good: BK=32, BN=64) ----------------
// out[r,c] = post( x[r,:] @ W[:,c] ), post = (+bias) -> relu -> (*dinv[r])
// __launch_bounds__(256,4) caps VGPR at 128 (R3 spilled at 256 VGPR);
// '#pragma unroll 1' on the K-tile loop prevents whole-kernel flattening.
// RPT-dependent branches are `if constexpr` (R6 compile failure).

template <int K, int NOUT, int BM, bool RELU, bool BIAS, bool SCALE>
__global__ __launch_bounds__(256, 4) void k_gemm(const float* __restrict__ x,
        const float* __restrict__ W, const float* __restrict__ bias,
        const float* __restrict__ dinv, float* __restrict__ out, int nrows) {
    constexpr int BK = 32, BN = 64;
    constexpr int NCB = NOUT / BN;  // column blocks per row
    constexpr int RPT = BM / 16;    // rows per thread (8 or 4)
    __shared__ float xt[BK * BM];
    __shared__ float wt[BK * BN];

    int tid = threadIdx.x;
    int rg = tid & 15;  // row group
    int cg = tid >> 4;  // col group: cols cg*4..+3 of the 64-col strip
    int row0 = (blockIdx.x / NCB) * BM;
    int col0 = (blockIdx.x % NCB) * BN;

    float acc[RPT][4] = {};

#pragma unroll 1
    for (int kk = 0; kk < K; kk += BK) {
        __syncthreads();
        // ---- x tile: BM rows x 32 k, coalesced float4, swizzled transpose store
#pragma unroll
        for (int t = 0; t < BM / 32; ++t) {
            int idx = tid + t * 256;
            int r = idx >> 3;
            int kc = (idx & 7) * 4;
            float4 v = make_float4(0.f, 0.f, 0.f, 0.f);
            int gr = row0 + r;
            if (gr < nrows) v = *reinterpret_cast<const float4*>(&x[(size_t)gr * K + kk + kc]);
            int rc = r ^ kc; // kc in {0..28}: swizzle within 32-row stripe
            xt[(kc + 0) * BM + rc] = v.x;
            xt[(kc + 1) * BM + rc] = v.y;
            xt[(kc + 2) * BM + rc] = v.z;
            xt[(kc + 3) * BM + rc] = v.w;
        }
        // ---- W tile: 32 k x 64 n
#pragma unroll
        for (int t = 0; t < 2; ++t) {
            int idx = tid + t * 256;
            int k = idx >> 4;
            int c = (idx & 15) * 4;
            *reinterpret_cast<float4*>(&wt[k * BN + c]) =
                *reinterpret_cast<const float4*>(&W[(size_t)(kk + k) * NOUT + col0 + c]);
        }
        __syncthreads();

#pragma unroll
        for (int k = 0; k < BK; ++k) {
            int s = k & 28;
            float4 wv = *reinterpret_cast<const float4*>(&wt[k * BN + cg * 4]);
            float wr[4] = {wv.x, wv.y, wv.z, wv.w};
            float xr[RPT];
            float4 x0 = *reinterpret_cast<const float4*>(&xt[k * BM + ((rg * 4) ^ s)]);
            xr[0] = x0.x; xr[1] = x0.y; xr[2] = x0.z; xr[3] = x0.w;
            if constexpr (RPT == 8) {
                float4 x1 = *reinterpret_cast<const float4*>(&xt[k * BM + (((rg * 4) ^ s) + 64)]);
                xr[4] = x1.x; xr[5] = x1.y; xr[6] = x1.z; xr[7] = x1.w;
            }
#pragma unroll
            for (int a = 0; a < RPT; a++)
#pragma unroll
                for (int b = 0; b < 4; b++) acc[a][b] += xr[a] * wr[b];
        }
    }

    float bv[4];
    if (BIAS) {
#pragma unroll
        for (int b = 0; b < 4; b++) bv[b] = bias[col0 + cg * 4 + b];
    }
#pragma unroll
    for (int a = 0; a < RPT; a++) {
        int r = rg * 4 + (a & 3) + ((a >= 4) ? 64 : 0);
        int gr = row0 + r;
        if (gr >= nrows) continue;
        float d = SCALE ? dinv[gr] : 1.f;
        float o[4];
#pragma unroll
        for (int b = 0; b < 4; b++) {
            float v = acc[a][b];
            if (BIAS) v += bv[b];
            if (RELU) v = fmaxf(v, 0.f);
            o[b] = v * d;
        }
        *reinterpret_cast<float4*>(&out[(size_t)gr * NOUT + col0 + cg * 4]) =
            make_float4(o[0], o[1], o[2], o[3]);
    }
}

// ---------------- launch ----------------

extern "C" void kernel_launch(void* const* d_in, const int* in_sizes, int n_in,
                              void* d_out, int out_size, void* d_ws, size_t ws_size,
                              hipStream_t stream) {
    const float* feat = (const float*)d_in[0]; // [N, 64]
    const float* W1 = (const float*)d_in[1];   // [64, 128]
    const float* b1 = (const float*)d_in[2];
    const float* W2 = (const float*)d_in[3];   // [128, 128]
    const float* b2 = (const float*)d_in[4];
    const float* W3 = (const float*)d_in[5];   // [128, 64]
    const float* b3 = (const float*)d_in[6];
    const int* ei = (const int*)d_in[7];       // [2, E]
    const int* row = ei;
    const int* col = ei + N_EDGES;
    float* out = (float*)d_out;

    // workspace bump allocator (256B aligned)
    char* ws = (char*)d_ws;
    size_t off = 0;
    auto alloc = [&](size_t bytes) {
        void* p = ws + off;
        off = alignUp(off + bytes, 256);
        return p;
    };
    float* B0      = (float*)alloc((size_t)N_NODES * 128 * 4);
    float* B1      = (float*)alloc((size_t)N_NODES * 128 * 4);
    float* dinv    = (float*)alloc((size_t)N_NODES * 4);
    int*   count   = (int*)alloc((size_t)N_NODES * 4);
    int*   offsets = (int*)alloc((size_t)N_NODES * 4);
    int*   bsum    = (int*)alloc(1024);
    int*   csr_col = (int*)alloc((size_t)(N_EDGES + 64) * 4); // +64 pad for over-read
    // rank (800K ints) overlays B0: dead until the first aggregation writes
    // B0 (after scatter consumes rank).
    int* rank = (int*)B0;
    // featS (N x 64) overlays B1: dead before GEMM1 writes B1.
    float* featS   = B1;

    const int eb = (N_EDGES + 255) / 256; // 3125
    const int rb128 = (N_NODES + 127) / 128; // 391
    const int rb64  = (N_NODES + 63) / 64;   // 782
    const int agg_grid = N_NODES / 4;        // 12500 (one node per wave)

    // CSR build (every call — no cached state allowed)
    k_zero_i32<<<(N_NODES + 255) / 256, 256, 0, stream>>>(count, N_NODES);
    k_count<<<eb, 256, 0, stream>>>(row, count, rank, csr_col + N_EDGES);
    k_blocksum<<<SCAN_BLOCKS, 256, 0, stream>>>(count, bsum);
    k_scan_bsum<<<1, 256, 0, stream>>>(bsum);
    k_scan_final<<<SCAN_BLOCKS, 256, 0, stream>>>(count, bsum, offsets, dinv);
    // atomic-free scatter + fused feature prescale (same 800000-thread grid)
    k_scatter<<<eb, 256, 0, stream>>>(row, col, offsets, rank, csr_col, feat, dinv, featS);

    // Layer 1: agg1 = A_hat@feat (F=64), then x1' = dinv .* relu(agg1@W1+b1)
    k_agg64<false><<<agg_grid, 256, 0, stream>>>(featS, B0, csr_col, offsets, count, dinv, nullptr);
    k_gemm<64, 128, 128, true, true, true><<<rb128 * 2, 256, 0, stream>>>(B0, W1, b1, dinv, B1, N_NODES);

    // Layer 2: agg2 = A_hat@x1 (F=128), then x2 = relu(agg2@W2+b2) (unscaled)
    k_agg128<false><<<agg_grid, 256, 0, stream>>>(B1, B0, csr_col, offsets, count, dinv, nullptr);
    k_gemm<128, 128, 128, true, true, false><<<rb128 * 2, 256, 0, stream>>>(B0, W2, b2, dinv, B1, N_NODES);

    // Layer 3: h3' = dinv .* (x2@W3), then out = A_hat-agg + b3
    k_gemm<128, 64, 64, false, false, true><<<rb64, 256, 0, stream>>>(B1, W3, nullptr, dinv, B0, N_NODES);
    k_agg64<true><<<agg_grid, 256, 0, stream>>>(B0, out, csr_col, offsets, count, dinv, b3);
}

// Round 15
// 220.194 us; speedup vs baseline: 2.5437x; 1.1914x over previous
//
#include <hip/hip_runtime.h>

#define N_NODES 50000
#define N_EDGES 800000

#define SCAN_CHUNK 256
#define SCAN_BLOCKS ((N_NODES + SCAN_CHUNK - 1) / SCAN_CHUNK) // 196

static inline size_t alignUp(size_t x, size_t a) { return (x + a - 1) & ~(a - 1); }

// fp16 vector types (scalar-element ext vectors; R7: HIP vector classes are
// rejected by some builtins, ext vectors always work)
typedef _Float16 h2 __attribute__((ext_vector_type(2)));
typedef _Float16 h4 __attribute__((ext_vector_type(4)));

// ---------------- CSR build (R14-proven rank-split, atomic-free scatter) ----

__global__ void k_zero_i32(int* __restrict__ p, int n) {
    int i = blockIdx.x * 256 + threadIdx.x;
    if (i < n) p[i] = 0;
}

// count degrees + save per-edge rank; first 64 threads zero csr_col pad
__global__ void k_count(const int* __restrict__ row, int* __restrict__ count,
                        int* __restrict__ rank, int* __restrict__ pad) {
    int e = blockIdx.x * 256 + threadIdx.x;
    if (e < 64) pad[e] = 0;
    if (e < N_EDGES) rank[e] = atomicAdd(&count[row[e]], 1);
}

__global__ void k_blocksum(const int* __restrict__ count, int* __restrict__ bsum) {
    __shared__ int s[256];
    int t = threadIdx.x;
    int i = blockIdx.x * 256 + t;
    int v = (i < N_NODES) ? count[i] : 0;
    s[t] = v;
    __syncthreads();
    for (int off = 128; off > 0; off >>= 1) {
        if (t < off) s[t] += s[t + off];
        __syncthreads();
    }
    if (t == 0) bsum[blockIdx.x] = s[0];
}

__global__ void k_scan_bsum(int* __restrict__ bsum) {
    __shared__ int s[256];
    int t = threadIdx.x;
    int v = (t < SCAN_BLOCKS) ? bsum[t] : 0;
    s[t] = v;
    __syncthreads();
    for (int off = 1; off < 256; off <<= 1) {
        int add = (t >= off) ? s[t - off] : 0;
        __syncthreads();
        s[t] += add;
        __syncthreads();
    }
    if (t < SCAN_BLOCKS) bsum[t] = s[t] - v; // exclusive
}

__global__ void k_scan_final(const int* __restrict__ count, const int* __restrict__ bsum,
                             int* __restrict__ offsets, float* __restrict__ dinv) {
    __shared__ int s[256];
    int t = threadIdx.x;
    int i = blockIdx.x * 256 + t;
    int v = (i < N_NODES) ? count[i] : 0;
    s[t] = v;
    __syncthreads();
    for (int off = 1; off < 256; off <<= 1) {
        int add = (t >= off) ? s[t - off] : 0;
        __syncthreads();
        s[t] += add;
        __syncthreads();
    }
    if (i < N_NODES) {
        offsets[i] = s[t] - v + bsum[blockIdx.x];
        dinv[i]    = rsqrtf((float)(v + 1)); // +1 self-loop; always > 0
    }
}

// atomic-free scatter: pos = offsets[row] + rank. Fused fp16 prescale:
// featS[node,:] = fp16(dinv[node] * feat[node,:]) (4 floats -> 4 halfs/thread)
__global__ void k_scatter(const int* __restrict__ row, const int* __restrict__ col,
                          const int* __restrict__ offsets, const int* __restrict__ rank,
                          int* __restrict__ csr_col,
                          const float* __restrict__ feat, const float* __restrict__ dinv,
                          _Float16* __restrict__ featS) {
    int e = blockIdx.x * 256 + threadIdx.x;
    if (e < N_EDGES) {
        int node = e >> 4;
        float d = dinv[node];
        float4 v = reinterpret_cast<const float4*>(feat)[e];
        h4 hv = {(_Float16)(v.x * d), (_Float16)(v.y * d),
                 (_Float16)(v.z * d), (_Float16)(v.w * d)};
        reinterpret_cast<h4*>(featS)[e] = hv;
        // scatter (no atomic: rank precomputed in k_count)
        int r = row[e];
        csr_col[offsets[r] + rank[e]] = col[e];
    }
}

// ---------------- Aggregation over PRE-SCALED fp16 rows ----------------
// out[i] = dinv_i * ( h'[i] + sum_c h'[c] ) (+bias), h' = fp16(dinv .* h)
// Input rows fp16 (halved L3->L2 fill — the R5-R11-proven agg bound);
// accumulate fp32; output fp32. csr_col padded (+64 zeros), over-read safe.

// F=128: row = 256B; 64 lanes x h2(4B) = one row per instruction;
// 8 edges per batch (8 gathers in flight).
template <bool BIAS>
__global__ __launch_bounds__(256) void k_agg128(const _Float16* __restrict__ hs, float* __restrict__ out,
        const int* __restrict__ csr_col, const int* __restrict__ offsets,
        const int* __restrict__ count, const float* __restrict__ dinv,
        const float* __restrict__ bias) {
    int lane = threadIdx.x & 63;
    int node = blockIdx.x * 4 + (threadIdx.x >> 6);
    const char* base = (const char*)hs;
    uint32_t lo = (uint32_t)lane << 2; // h2 byte offset within 256B row

    float ax[8], ay[8];
#pragma unroll
    for (int u = 0; u < 8; u++) { ax[u] = 0.f; ay[u] = 0.f; }

    int n = count[node];
    const int* cp = csr_col + offsets[node];

    int e = 0;
    for (; e + 8 <= n; e += 8) {
        int c[8];
#pragma unroll
        for (int u = 0; u < 8; u++) c[u] = cp[e + u];
#pragma unroll
        for (int u = 0; u < 8; u++) {
            h2 v = *reinterpret_cast<const h2*>(base + (((uint32_t)c[u] << 8) + lo));
            ax[u] += (float)v.x; ay[u] += (float)v.y;
        }
    }
    if (e < n) { // one predicated batch covers rem 1..7
        int c[8];
#pragma unroll
        for (int u = 0; u < 8; u++) c[u] = cp[e + u]; // padded, safe
#pragma unroll
        for (int u = 0; u < 8; u++) {
            h2 v = *reinterpret_cast<const h2*>(base + (((uint32_t)c[u] << 8) + lo));
            if (e + u < n) { ax[u] += (float)v.x; ay[u] += (float)v.y; }
        }
    }

    float sx = 0.f, sy = 0.f;
#pragma unroll
    for (int u = 0; u < 8; u++) { sx += ax[u]; sy += ay[u]; }
    h2 self = *reinterpret_cast<const h2*>(base + (((uint32_t)node << 8) + lo));
    float d = dinv[node];
    float ox = (sx + (float)self.x) * d, oy = (sy + (float)self.y) * d;
    if (BIAS) { ox += bias[2 * lane]; oy += bias[2 * lane + 1]; }
    reinterpret_cast<float2*>(out)[(size_t)node * 64 + lane] = make_float2(ox, oy);
}

// F=64: row = 128B; 16 lanes x h4(8B) = one row, 4 edges per instruction
// -> 32 edges per batch; scalar bounds via readfirstlane.
template <bool BIAS>
__global__ __launch_bounds__(256) void k_agg64(const _Float16* __restrict__ hs, float* __restrict__ out,
        const int* __restrict__ csr_col, const int* __restrict__ offsets,
        const int* __restrict__ count, const float* __restrict__ dinv,
        const float* __restrict__ bias) {
    int lane = threadIdx.x & 63;
    int node = blockIdx.x * 4 + (threadIdx.x >> 6);
    int q = lane >> 4;        // edge sub-slot (0..3)
    int f4 = lane & 15;       // h4 index within 128B row
    const char* base = (const char*)hs;
    uint32_t fo = (uint32_t)f4 << 3;

    int n = __builtin_amdgcn_readfirstlane(count[node]);
    int start = __builtin_amdgcn_readfirstlane(offsets[node]);
    const int* cp = csr_col + start;

    float4 a0 = make_float4(0.f, 0.f, 0.f, 0.f);
    float4 a1 = make_float4(0.f, 0.f, 0.f, 0.f);

    int e = 0;
    for (; e + 32 <= n; e += 32) {
        int c[8];
#pragma unroll
        for (int u = 0; u < 8; u++) c[u] = cp[e + 4 * u + q];
        h4 v[8];
#pragma unroll
        for (int u = 0; u < 8; u++)
            v[u] = *reinterpret_cast<const h4*>(base + (((uint32_t)c[u] << 7) + fo));
#pragma unroll
        for (int u = 0; u < 8; u += 2) {
            a0.x += (float)v[u].x; a0.y += (float)v[u].y;
            a0.z += (float)v[u].z; a0.w += (float)v[u].w;
            a1.x += (float)v[u+1].x; a1.y += (float)v[u+1].y;
            a1.z += (float)v[u+1].z; a1.w += (float)v[u+1].w;
        }
    }
    if (e < n) {
        int c[8];
#pragma unroll
        for (int u = 0; u < 8; u++) c[u] = cp[e + 4 * u + q]; // padded, safe
        h4 v[8];
#pragma unroll
        for (int u = 0; u < 8; u++)
            v[u] = *reinterpret_cast<const h4*>(base + (((uint32_t)c[u] << 7) + fo));
#pragma unroll
        for (int u = 0; u < 8; u++) {
            if (e + 4 * u + q < n) {
                a0.x += (float)v[u].x; a0.y += (float)v[u].y;
                a0.z += (float)v[u].z; a0.w += (float)v[u].w;
            }
        }
    }

    float sx = a0.x + a1.x, sy = a0.y + a1.y, sz = a0.z + a1.z, sw = a0.w + a1.w;
    sx += __shfl_xor(sx, 16); sy += __shfl_xor(sy, 16);
    sz += __shfl_xor(sz, 16); sw += __shfl_xor(sw, 16);
    sx += __shfl_xor(sx, 32); sy += __shfl_xor(sy, 32);
    sz += __shfl_xor(sz, 32); sw += __shfl_xor(sw, 32);
    if (q == 0) {
        h4 self = *reinterpret_cast<const h4*>(base + (((uint32_t)node << 7) + fo));
        float d = dinv[node];
        float ox = (sx + (float)self.x) * d, oy = (sy + (float)self.y) * d;
        float oz = (sz + (float)self.z) * d, ow = (sw + (float)self.w) * d;
        if (BIAS) {
            float4 bv = *reinterpret_cast<const float4*>(&bias[f4 * 4]);
            ox += bv.x; oy += bv.y; oz += bv.z; ow += bv.w;
        }
        *reinterpret_cast<float4*>((char*)out + ((uint32_t)node << 8) + (fo << 1)) =
            make_float4(ox, oy, oz, ow);
    }
}

// ---------------- fp32 GEMM (R4 known-good) + optional fp16 epilogue ----
// out[r,c] = post( x[r,:] @ W[:,c] ), post = (+bias) -> relu -> (*dinv[r])
// HOUT: store output as fp16 (for gather consumers). Input always fp32.

template <int K, int NOUT, int BM, bool RELU, bool BIAS, bool SCALE, bool HOUT>
__global__ __launch_bounds__(256, 4) void k_gemm(const float* __restrict__ x,
        const float* __restrict__ W, const float* __restrict__ bias,
        const float* __restrict__ dinv, void* __restrict__ out, int nrows) {
    constexpr int BK = 32, BN = 64;
    constexpr int NCB = NOUT / BN;  // column blocks per row
    constexpr int RPT = BM / 16;    // rows per thread (8 or 4)
    __shared__ float xt[BK * BM];
    __shared__ float wt[BK * BN];

    int tid = threadIdx.x;
    int rg = tid & 15;  // row group
    int cg = tid >> 4;  // col group: cols cg*4..+3 of the 64-col strip
    int row0 = (blockIdx.x / NCB) * BM;
    int col0 = (blockIdx.x % NCB) * BN;

    float acc[RPT][4] = {};

#pragma unroll 1
    for (int kk = 0; kk < K; kk += BK) {
        __syncthreads();
        // ---- x tile: BM rows x 32 k, coalesced float4, swizzled transpose store
#pragma unroll
        for (int t = 0; t < BM / 32; ++t) {
            int idx = tid + t * 256;
            int r = idx >> 3;
            int kc = (idx & 7) * 4;
            float4 v = make_float4(0.f, 0.f, 0.f, 0.f);
            int gr = row0 + r;
            if (gr < nrows) v = *reinterpret_cast<const float4*>(&x[(size_t)gr * K + kk + kc]);
            int rc = r ^ kc; // kc in {0..28}: swizzle within 32-row stripe
            xt[(kc + 0) * BM + rc] = v.x;
            xt[(kc + 1) * BM + rc] = v.y;
            xt[(kc + 2) * BM + rc] = v.z;
            xt[(kc + 3) * BM + rc] = v.w;
        }
        // ---- W tile: 32 k x 64 n
#pragma unroll
        for (int t = 0; t < 2; ++t) {
            int idx = tid + t * 256;
            int k = idx >> 4;
            int c = (idx & 15) * 4;
            *reinterpret_cast<float4*>(&wt[k * BN + c]) =
                *reinterpret_cast<const float4*>(&W[(size_t)(kk + k) * NOUT + col0 + c]);
        }
        __syncthreads();

#pragma unroll
        for (int k = 0; k < BK; ++k) {
            int s = k & 28;
            float4 wv = *reinterpret_cast<const float4*>(&wt[k * BN + cg * 4]);
            float wr[4] = {wv.x, wv.y, wv.z, wv.w};
            float xr[RPT];
            float4 x0 = *reinterpret_cast<const float4*>(&xt[k * BM + ((rg * 4) ^ s)]);
            xr[0] = x0.x; xr[1] = x0.y; xr[2] = x0.z; xr[3] = x0.w;
            if constexpr (RPT == 8) {
                float4 x1 = *reinterpret_cast<const float4*>(&xt[k * BM + (((rg * 4) ^ s) + 64)]);
                xr[4] = x1.x; xr[5] = x1.y; xr[6] = x1.z; xr[7] = x1.w;
            }
#pragma unroll
            for (int a = 0; a < RPT; a++)
#pragma unroll
                for (int b = 0; b < 4; b++) acc[a][b] += xr[a] * wr[b];
        }
    }

    float bv[4];
    if (BIAS) {
#pragma unroll
        for (int b = 0; b < 4; b++) bv[b] = bias[col0 + cg * 4 + b];
    }
#pragma unroll
    for (int a = 0; a < RPT; a++) {
        int r = rg * 4 + (a & 3) + ((a >= 4) ? 64 : 0);
        int gr = row0 + r;
        if (gr >= nrows) continue;
        float d = SCALE ? dinv[gr] : 1.f;
        float o[4];
#pragma unroll
        for (int b = 0; b < 4; b++) {
            float v = acc[a][b];
            if (BIAS) v += bv[b];
            if (RELU) v = fmaxf(v, 0.f);
            o[b] = v * d;
        }
        if constexpr (HOUT) {
            h4 ho = {(_Float16)o[0], (_Float16)o[1], (_Float16)o[2], (_Float16)o[3]};
            *reinterpret_cast<h4*>((_Float16*)out + (size_t)gr * NOUT + col0 + cg * 4) = ho;
        } else {
            *reinterpret_cast<float4*>((float*)out + (size_t)gr * NOUT + col0 + cg * 4) =
                make_float4(o[0], o[1], o[2], o[3]);
        }
    }
}

// ---------------- launch ----------------

extern "C" void kernel_launch(void* const* d_in, const int* in_sizes, int n_in,
                              void* d_out, int out_size, void* d_ws, size_t ws_size,
                              hipStream_t stream) {
    const float* feat = (const float*)d_in[0]; // [N, 64]
    const float* W1 = (const float*)d_in[1];   // [64, 128]
    const float* b1 = (const float*)d_in[2];
    const float* W2 = (const float*)d_in[3];   // [128, 128]
    const float* b2 = (const float*)d_in[4];
    const float* W3 = (const float*)d_in[5];   // [128, 64]
    const float* b3 = (const float*)d_in[6];
    const int* ei = (const int*)d_in[7];       // [2, E]
    const int* row = ei;
    const int* col = ei + N_EDGES;
    float* out = (float*)d_out;

    // workspace bump allocator (256B aligned)
    char* ws = (char*)d_ws;
    size_t off = 0;
    auto alloc = [&](size_t bytes) {
        void* p = ws + off;
        off = alignUp(off + bytes, 256);
        return p;
    };
    float* B0      = (float*)alloc((size_t)N_NODES * 128 * 4);
    float* B1      = (float*)alloc((size_t)N_NODES * 128 * 4);
    float* dinv    = (float*)alloc((size_t)N_NODES * 4);
    int*   count   = (int*)alloc((size_t)N_NODES * 4);
    int*   offsets = (int*)alloc((size_t)N_NODES * 4);
    int*   bsum    = (int*)alloc(1024);
    int*   csr_col = (int*)alloc((size_t)(N_EDGES + 64) * 4); // +64 pad for over-read
    // rank (800K ints) overlays B0: dead once scatter consumes it (before
    // the first aggregation writes B0).
    int* rank = (int*)B0;
    // featS (N x 64 fp16 = 6.4MB) overlays B1: dead before GEMM1 writes B1.
    _Float16* featS = (_Float16*)B1;
    // fp16 views for intermediate gather matrices
    _Float16* B1h = (_Float16*)B1; // x1' (post-GEMM1)
    _Float16* B0h = (_Float16*)B0; // h3' (post-GEMM3)

    const int eb = (N_EDGES + 255) / 256; // 3125
    const int rb128 = (N_NODES + 127) / 128; // 391
    const int rb64  = (N_NODES + 63) / 64;   // 782
    const int agg_grid = N_NODES / 4;        // 12500 (one node per wave)

    // CSR build (every call — no cached state allowed)
    k_zero_i32<<<(N_NODES + 255) / 256, 256, 0, stream>>>(count, N_NODES);
    k_count<<<eb, 256, 0, stream>>>(row, count, rank, csr_col + N_EDGES);
    k_blocksum<<<SCAN_BLOCKS, 256, 0, stream>>>(count, bsum);
    k_scan_bsum<<<1, 256, 0, stream>>>(bsum);
    k_scan_final<<<SCAN_BLOCKS, 256, 0, stream>>>(count, bsum, offsets, dinv);
    // atomic-free scatter + fused fp16 feature prescale
    k_scatter<<<eb, 256, 0, stream>>>(row, col, offsets, rank, csr_col, feat, dinv, featS);

    // Layer 1: agg1 = A_hat@feat (fp16 gather), then x1' = fp16(dinv.*relu(agg1@W1+b1))
    k_agg64<false><<<agg_grid, 256, 0, stream>>>(featS, B0, csr_col, offsets, count, dinv, nullptr);
    k_gemm<64, 128, 128, true, true, true, true><<<rb128 * 2, 256, 0, stream>>>(B0, W1, b1, dinv, B1h, N_NODES);

    // Layer 2: agg2 = A_hat@x1 (fp16 gather), then x2 = relu(agg2@W2+b2) (fp32)
    k_agg128<false><<<agg_grid, 256, 0, stream>>>(B1h, B0, csr_col, offsets, count, dinv, nullptr);
    k_gemm<128, 128, 128, true, true, false, false><<<rb128 * 2, 256, 0, stream>>>(B0, W2, b2, dinv, B1, N_NODES);

    // Layer 3: h3' = fp16(dinv .* (x2@W3)), then out = A_hat-agg + b3 (fp32)
    k_gemm<128, 64, 64, false, false, true, true><<<rb64, 256, 0, stream>>>(B1, W3, nullptr, dinv, B0h, N_NODES);
    k_agg64<true><<<agg_grid, 256, 0, stream>>>(B0h, out, csr_col, offsets, count, dinv, b3);
}